// Round 7
// baseline (110.963 us; speedup 1.0000x reference)
//
#include <hip/hip_runtime.h>

#define LNUM 12
#define TNUM 12
#define NPASS 7   // 1 initial pass + HORIZON=6

// ---------------------------------------------------------------------------
// Prep kernel: pre-scale weights/biases ONCE into d_ws so the main kernel
// does zero scaling work per step. Layout (floats):
//   [0..11]   wi0' = -log2e * w_ih[l][0]
//   [12..23]  wi1' = -log2e * w_ih[l][1]
//   [24..35]  wi2' = 2log2e * w_ih[l][2]
//   [36..47]  wh0' = -log2e * w_hh[l][0]
//   [48..59]  wh1' = -log2e * w_hh[l][1]
//   [60..71]  wh2' = 2log2e * w_hh[l][2]
//   [72..83]  b0'  = -log2e * (b_ih[l][0] + b_hh[l][0])
//   [84..95]  b1'  = -log2e * (b_ih[l][1] + b_hh[l][1])
//   [96..107] bi2' = 2log2e * b_ih[l][2]
//   [108..119] bh2'= 2log2e * b_hh[l][2]
// ---------------------------------------------------------------------------
__global__ void gru_prep_kernel(const float* __restrict__ w_ih,
                                const float* __restrict__ w_hh,
                                const float* __restrict__ b_ih,
                                const float* __restrict__ b_hh,
                                float* __restrict__ ws) {
    const float NL2E = -1.4426950408889634f; // -log2(e)
    const float TL2E =  2.8853900817779268f; //  2*log2(e)
    int j = threadIdx.x;
    if (j >= 10 * LNUM) return;
    int g = j / LNUM, l = j % LNUM;
    float v;
    switch (g) {
        case 0: v = NL2E * w_ih[3*l+0]; break;
        case 1: v = NL2E * w_ih[3*l+1]; break;
        case 2: v = TL2E * w_ih[3*l+2]; break;
        case 3: v = NL2E * w_hh[3*l+0]; break;
        case 4: v = NL2E * w_hh[3*l+1]; break;
        case 5: v = TL2E * w_hh[3*l+2]; break;
        case 6: v = NL2E * (b_ih[3*l+0] + b_hh[3*l+0]); break;
        case 7: v = NL2E * (b_ih[3*l+1] + b_hh[3*l+1]); break;
        case 8: v = TL2E * b_ih[3*l+2]; break;
        default: v = TL2E * b_hh[3*l+2]; break;
    }
    ws[j] = v;
}

// ---------------------------------------------------------------------------
// Main kernel: one thread per (b,n) scalar-GRU chain, all state in registers.
// Weights arrive pre-scaled (uniform -> SGPR); biases held in VGPRs so each
// gate pre-activation is a single v_fma (1 SGPR operand max per VALU op).
// Per layer-step: 14 VALU + 5 transcendental (shared-rcp double sigmoid).
// ---------------------------------------------------------------------------
__global__ __launch_bounds__(256, 1)
void gru_chain_kernel(const float* __restrict__ x,
                      const float* __restrict__ ws,
                      float* __restrict__ out,
                      int total) {
    const int tid = blockIdx.x * blockDim.x + threadIdx.x;
    if (tid >= total) return;

    const float* __restrict__ wi0 = ws +   0;
    const float* __restrict__ wi1 = ws +  12;
    const float* __restrict__ wi2 = ws +  24;
    const float* __restrict__ wh0 = ws +  36;
    const float* __restrict__ wh1 = ws +  48;
    const float* __restrict__ wh2 = ws +  60;

    // Biases -> VGPR arrays (static-indexed, fully unrolled -> registers).
    float vb0[LNUM], vb1[LNUM], vbi2[LNUM], vbh2[LNUM];
#pragma unroll
    for (int l = 0; l < LNUM; ++l) {
        vb0[l]  = ws[72  + l];
        vb1[l]  = ws[84  + l];
        vbi2[l] = ws[96  + l];
        vbh2[l] = ws[108 + l];
    }

    // Load this chain's 12 inputs (contiguous 48B -> 3x float4).
    float seq[TNUM];
    const float4* xv = reinterpret_cast<const float4*>(x + (size_t)tid * TNUM);
#pragma unroll
    for (int i = 0; i < TNUM / 4; ++i) {
        float4 v = xv[i];
        seq[i*4+0] = v.x; seq[i*4+1] = v.y; seq[i*4+2] = v.z; seq[i*4+3] = v.w;
    }

    float h[LNUM];
#pragma unroll
    for (int l = 0; l < LNUM; ++l) h[l] = 0.0f;

#pragma unroll 1   // pass loop rolled (code size); t & l fully unrolled
    for (int p = 0; p < NPASS; ++p) {
#pragma unroll
        for (int t = 0; t < TNUM; ++t) {
            float inp = seq[t];
#pragma unroll
            for (int l = 0; l < LNUM; ++l) {
                // gate pre-activations, already scaled by -log2e / 2log2e
                float ar = fmaf(inp, wi0[l], fmaf(h[l], wh0[l], vb0[l]));
                float az = fmaf(inp, wi1[l], fmaf(h[l], wh1[l], vb1[l]));
                float gn = fmaf(inp, wi2[l], vbi2[l]);
                float hg = fmaf(h[l], wh2[l], vbh2[l]);

                float er = __builtin_amdgcn_exp2f(ar);   // exp(-(a_r))
                float ez = __builtin_amdgcn_exp2f(az);   // exp(-(a_z))
                float ea = 1.0f + er;
                float eb = 1.0f + ez;
                // shared reciprocal: r = 1/ea, z = 1/eb with ONE v_rcp
                float D  = __builtin_amdgcn_rcpf(ea * eb);
                float r  = D * eb;
                float z  = D * ea;

                float en = __builtin_amdgcn_exp2f(fmaf(r, hg, gn)); // exp(2p·ln2e)
                float u  = __builtin_amdgcn_rcpf(1.0f + en);
                float n  = fmaf(-2.0f, u, 1.0f);          // tanh(p)

                float hn = fmaf(z, h[l], fmaf(-z, n, n)); // (1-z)n + z*h
                h[l] = hn;
                inp  = hn;
            }
            seq[t] = inp;  // top-layer output feeds next pass at step t
        }
    }

#pragma unroll
    for (int l = 0; l < LNUM; ++l) {
        out[(size_t)l * total + tid] = h[l];
    }
}

extern "C" void kernel_launch(void* const* d_in, const int* in_sizes, int n_in,
                              void* d_out, int out_size, void* d_ws, size_t ws_size,
                              hipStream_t stream) {
    const float* x    = (const float*)d_in[0];
    const float* w_ih = (const float*)d_in[1];
    const float* w_hh = (const float*)d_in[2];
    const float* b_ih = (const float*)d_in[3];
    const float* b_hh = (const float*)d_in[4];
    float* out = (float*)d_out;
    float* ws  = (float*)d_ws;

    gru_prep_kernel<<<1, 128, 0, stream>>>(w_ih, w_hh, b_ih, b_hh, ws);

    const int total = in_sizes[0] / TNUM;   // B*N = 65536
    const int block = 256;
    const int grid  = (total + block - 1) / block;
    gru_chain_kernel<<<grid, block, 0, stream>>>(x, ws, out, total);
}